// Round 5
// baseline (27.012 us; speedup 1.0000x reference)
//
#include <hip/hip_runtime.h>
#include <math.h>

#define BLK 256
#define SUBC 64           // cloud points per LDS stage pass (= csize at nchunk=64)
#define SPT 8             // grid points per thread (amortizes broadcast ds_read)
#define INF 3.4e38f

// Kernel 1: each thread owns SPT grid points; block stages a cloud chunk into
// LDS packed as float4{y0,y1,y2, 0.5*|y|^2}; inner loop = broadcast
// ds_read_b128 + FMA/min3 chains on t_j = hy_j - x.y_j (Gram form).
// Stores u = hx + min_j t_j ; d = sqrt(max(2u,0)) applied in reduce.
__global__ __launch_bounds__(BLK, 2) void sdf_partial_min(
    const float* __restrict__ grid,   // [B,S,3]
    const float* __restrict__ gts,    // [B,N,3]
    const float* __restrict__ preds,  // [B,N,3]
    float* __restrict__ partial,      // [2][nchunk][B][S]
    int B, int S, int N, int nchunk, int csize)
{
    __shared__ float4 rawp4[SUBC * 3 / 4];   // 48 float4
    __shared__ float4 rawg4[SUBC * 3 / 4];
    __shared__ float4 lp[SUBC];
    __shared__ float4 lg[SUBC];

    const int tid   = threadIdx.x;
    const int stile = blockIdx.x;            // S / (BLK*SPT) tiles
    const int chunk = blockIdx.y;
    const int b     = blockIdx.z;

    const int s0 = stile * (BLK * SPT) + tid;   // gp i lives at s0 + i*BLK

    float x0[SPT], x1[SPT], x2[SPT], hx[SPT];
    #pragma unroll
    for (int i = 0; i < SPT; ++i) {
        const float* xp = grid + ((size_t)b * S + s0 + i * BLK) * 3;
        x0[i] = -xp[0]; x1[i] = -xp[1]; x2[i] = -xp[2];
        hx[i] = 0.5f * (x0[i] * x0[i] + x1[i] * x1[i] + x2[i] * x2[i]);
    }

    const int n0 = chunk * csize;
    const float* pbase = preds + ((size_t)b * N + n0) * 3;
    const float* gbase = gts   + ((size_t)b * N + n0) * 3;

    float accp[SPT], accg[SPT];
    #pragma unroll
    for (int i = 0; i < SPT; ++i) { accp[i] = INF; accg[i] = INF; }

    for (int nn = 0; nn < csize; nn += SUBC) {
        __syncthreads();   // protect LDS reuse across stage passes
        // stage raw chunk (all offsets 16B-aligned)
        const float4* pv = (const float4*)(pbase + (size_t)nn * 3);
        const float4* gv = (const float4*)(gbase + (size_t)nn * 3);
        if (tid < SUBC * 3 / 4)
            rawp4[tid] = pv[tid];
        else if (tid < SUBC * 3 / 2)
            rawg4[tid - SUBC * 3 / 4] = gv[tid - SUBC * 3 / 4];
        __syncthreads();
        // pack with hy (3-stride LDS reads: 3 coprime 32 -> conflict-free)
        if (tid < SUBC) {
            const float* rp = (const float*)rawp4;
            float a = rp[3 * tid], c1 = rp[3 * tid + 1], c2 = rp[3 * tid + 2];
            lp[tid] = make_float4(a, c1, c2, 0.5f * (a * a + c1 * c1 + c2 * c2));
        } else if (tid < 2 * SUBC) {
            const int j = tid - SUBC;
            const float* rg = (const float*)rawg4;
            float a = rg[3 * j], c1 = rg[3 * j + 1], c2 = rg[3 * j + 2];
            lg[j] = make_float4(a, c1, c2, 0.5f * (a * a + c1 * c1 + c2 * c2));
        }
        __syncthreads();

        #pragma unroll 2
        for (int j = 0; j < SUBC; j += 4) {
            const float4 p0 = lp[j], p1 = lp[j + 1], p2 = lp[j + 2], p3 = lp[j + 3];
            #pragma unroll
            for (int i = 0; i < SPT; ++i) {
                float a0 = fmaf(x0[i], p0.x, fmaf(x1[i], p0.y, fmaf(x2[i], p0.z, p0.w)));
                float a1 = fmaf(x0[i], p1.x, fmaf(x1[i], p1.y, fmaf(x2[i], p1.z, p1.w)));
                float a2 = fmaf(x0[i], p2.x, fmaf(x1[i], p2.y, fmaf(x2[i], p2.z, p2.w)));
                float a3 = fmaf(x0[i], p3.x, fmaf(x1[i], p3.y, fmaf(x2[i], p3.z, p3.w)));
                const float m01 = fminf(a0, a1);
                const float m23 = fminf(a2, a3);
                accp[i] = fminf(fminf(accp[i], m01), m23);   // v_min3 shape
            }
            const float4 g0 = lg[j], g1 = lg[j + 1], g2 = lg[j + 2], g3 = lg[j + 3];
            #pragma unroll
            for (int i = 0; i < SPT; ++i) {
                float a0 = fmaf(x0[i], g0.x, fmaf(x1[i], g0.y, fmaf(x2[i], g0.z, g0.w)));
                float a1 = fmaf(x0[i], g1.x, fmaf(x1[i], g1.y, fmaf(x2[i], g1.z, g1.w)));
                float a2 = fmaf(x0[i], g2.x, fmaf(x1[i], g2.y, fmaf(x2[i], g2.z, g2.w)));
                float a3 = fmaf(x0[i], g3.x, fmaf(x1[i], g3.y, fmaf(x2[i], g3.z, g3.w)));
                const float m01 = fminf(a0, a1);
                const float m23 = fminf(a2, a3);
                accg[i] = fminf(fminf(accg[i], m01), m23);
            }
        }
    }

    const size_t sb = (size_t)B * S;
    #pragma unroll
    for (int i = 0; i < SPT; ++i) {
        const size_t base = (size_t)b * S + s0 + i * BLK;
        partial[(size_t)chunk * sb + base] = hx[i] + accp[i];
        partial[(size_t)(nchunk + chunk) * sb + base] = hx[i] + accg[i];
    }
}

// Kernel 2: per (tile,b): min over chunks, d = sqrt(max(2u,0)), |diff|,
// block-sum -> pb[b*ntile + tile].
__global__ __launch_bounds__(BLK) void sdf_reduce(
    const float* __restrict__ partial, float* __restrict__ pb,
    int B, int S, int nchunk)
{
    const int tile = blockIdx.x;
    const int b    = blockIdx.y;
    const int tid  = threadIdx.x;
    const int s    = tile * BLK + tid;

    const size_t sb = (size_t)B * S;
    const size_t base = (size_t)b * S + s;

    float mp = INF, mg = INF;
    #pragma unroll 8
    for (int c = 0; c < nchunk; ++c) {
        mp = fminf(mp, partial[(size_t)c * sb + base]);
        mg = fminf(mg, partial[(size_t)(nchunk + c) * sb + base]);
    }

    float v = fabsf(sqrtf(fmaxf(2.f * mp, 0.f)) - sqrtf(fmaxf(2.f * mg, 0.f)));

    #pragma unroll
    for (int off = 32; off > 0; off >>= 1)
        v += __shfl_down(v, off, 64);

    __shared__ float wsum[BLK / 64];
    if ((tid & 63) == 0) wsum[tid >> 6] = v;
    __syncthreads();
    if (tid == 0) {
        float t = 0.f;
        #pragma unroll
        for (int w = 0; w < BLK / 64; ++w) t += wsum[w];
        pb[b * gridDim.x + tile] = t;
    }
}

// Kernel 3: final tiny reduction.
__global__ __launch_bounds__(64) void sdf_final(
    const float* __restrict__ pb, float* __restrict__ out,
    int B, int S, int ntile)
{
    const int tid = threadIdx.x;
    float v = (tid < B * ntile) ? pb[tid] : 0.f;
    #pragma unroll
    for (int off = 8; off > 0; off >>= 1)
        v += __shfl_down(v, off, 16);
    if (tid < B * ntile && (tid & 15) == 0)
        out[tid / 16] = v / (float)S;
}

extern "C" void kernel_launch(void* const* d_in, const int* in_sizes, int n_in,
                              void* d_out, int out_size, void* d_ws, size_t ws_size,
                              hipStream_t stream) {
    const float* grid  = (const float*)d_in[0];
    const float* gts   = (const float*)d_in[1];
    const float* preds = (const float*)d_in[2];
    float* out = (float*)d_out;
    float* ws  = (float*)d_ws;

    const int B = 4, S = 4096, N = 4096;

    // partial needs 2*nchunk*B*S floats + 64 floats for pb
    const size_t per_chunk = (size_t)2 * B * S * sizeof(float);  // 128 KB
    int nchunk = 64;
    while (nchunk > 1 &&
           (size_t)nchunk * per_chunk + 256 > ws_size) nchunk >>= 1;
    const int csize = N / nchunk;    // 64 at nchunk=64 (multiple of SUBC)

    float* partial = ws;
    float* pb      = partial + (size_t)2 * nchunk * B * S;

    dim3 g1(S / (BLK * SPT), nchunk, B);   // (2, 64, 4) = 512 blocks
    sdf_partial_min<<<g1, BLK, 0, stream>>>(grid, gts, preds, partial,
                                            B, S, N, nchunk, csize);
    const int ntile = S / BLK;             // 16
    dim3 g2(ntile, B);
    sdf_reduce<<<g2, BLK, 0, stream>>>(partial, pb, B, S, nchunk);
    sdf_final<<<1, 64, 0, stream>>>(pb, out, B, S, ntile);
}

// Round 6
// 26.517 us; speedup vs baseline: 1.0187x; 1.0187x over previous
//
#include <hip/hip_runtime.h>
#include <math.h>

#define BLK 256
#define SUBC 64           // cloud points per LDS stage pass (= csize at nchunk=64)
#define SPT 4             // grid points per thread (amortizes broadcast ds_read)
#define INF 3.4e38f

// Kernel 1: each thread owns SPT grid points; block stages a cloud chunk into
// LDS packed as float4{y0,y1,y2, 0.5*|y|^2}; inner loop = broadcast
// ds_read_b128 + FMA/min3 chains on t_j = hy_j - x.y_j (Gram form).
// Stores u = hx + min_j t_j ; d = sqrt(max(2u,0)) applied in reduce.
__global__ __launch_bounds__(BLK) void sdf_partial_min(
    const float* __restrict__ grid,   // [B,S,3]
    const float* __restrict__ gts,    // [B,N,3]
    const float* __restrict__ preds,  // [B,N,3]
    float* __restrict__ partial,      // [2][nchunk][B][S]
    int B, int S, int N, int nchunk, int csize)
{
    __shared__ float4 rawp4[SUBC * 3 / 4];   // 48 float4
    __shared__ float4 rawg4[SUBC * 3 / 4];
    __shared__ float4 lp[SUBC];
    __shared__ float4 lg[SUBC];

    const int tid   = threadIdx.x;
    const int stile = blockIdx.x;            // S / (BLK*SPT) tiles
    const int chunk = blockIdx.y;
    const int b     = blockIdx.z;

    const int s0 = stile * (BLK * SPT) + tid;   // gp i lives at s0 + i*BLK

    float x0[SPT], x1[SPT], x2[SPT], hx[SPT];
    #pragma unroll
    for (int i = 0; i < SPT; ++i) {
        const float* xp = grid + ((size_t)b * S + s0 + i * BLK) * 3;
        x0[i] = -xp[0]; x1[i] = -xp[1]; x2[i] = -xp[2];
        hx[i] = 0.5f * (x0[i] * x0[i] + x1[i] * x1[i] + x2[i] * x2[i]);
    }

    const int n0 = chunk * csize;
    const float* pbase = preds + ((size_t)b * N + n0) * 3;
    const float* gbase = gts   + ((size_t)b * N + n0) * 3;

    float accp[SPT], accg[SPT];
    #pragma unroll
    for (int i = 0; i < SPT; ++i) { accp[i] = INF; accg[i] = INF; }

    for (int nn = 0; nn < csize; nn += SUBC) {
        __syncthreads();   // protect LDS reuse across stage passes
        // stage raw chunk (all offsets 16B-aligned)
        const float4* pv = (const float4*)(pbase + (size_t)nn * 3);
        const float4* gv = (const float4*)(gbase + (size_t)nn * 3);
        if (tid < SUBC * 3 / 4)
            rawp4[tid] = pv[tid];
        else if (tid < SUBC * 3 / 2)
            rawg4[tid - SUBC * 3 / 4] = gv[tid - SUBC * 3 / 4];
        __syncthreads();
        // pack with hy (3-stride LDS reads: 3 coprime 32 -> conflict-free)
        if (tid < SUBC) {
            const float* rp = (const float*)rawp4;
            float a = rp[3 * tid], c1 = rp[3 * tid + 1], c2 = rp[3 * tid + 2];
            lp[tid] = make_float4(a, c1, c2, 0.5f * (a * a + c1 * c1 + c2 * c2));
        } else if (tid < 2 * SUBC) {
            const int j = tid - SUBC;
            const float* rg = (const float*)rawg4;
            float a = rg[3 * j], c1 = rg[3 * j + 1], c2 = rg[3 * j + 2];
            lg[j] = make_float4(a, c1, c2, 0.5f * (a * a + c1 * c1 + c2 * c2));
        }
        __syncthreads();

        #pragma unroll 2
        for (int j = 0; j < SUBC; j += 4) {
            const float4 p0 = lp[j], p1 = lp[j + 1], p2 = lp[j + 2], p3 = lp[j + 3];
            #pragma unroll
            for (int i = 0; i < SPT; ++i) {
                float a0 = fmaf(x0[i], p0.x, fmaf(x1[i], p0.y, fmaf(x2[i], p0.z, p0.w)));
                float a1 = fmaf(x0[i], p1.x, fmaf(x1[i], p1.y, fmaf(x2[i], p1.z, p1.w)));
                float a2 = fmaf(x0[i], p2.x, fmaf(x1[i], p2.y, fmaf(x2[i], p2.z, p2.w)));
                float a3 = fmaf(x0[i], p3.x, fmaf(x1[i], p3.y, fmaf(x2[i], p3.z, p3.w)));
                const float m01 = fminf(a0, a1);
                const float m23 = fminf(a2, a3);
                accp[i] = fminf(fminf(accp[i], m01), m23);   // v_min3 shape
            }
            const float4 g0 = lg[j], g1 = lg[j + 1], g2 = lg[j + 2], g3 = lg[j + 3];
            #pragma unroll
            for (int i = 0; i < SPT; ++i) {
                float a0 = fmaf(x0[i], g0.x, fmaf(x1[i], g0.y, fmaf(x2[i], g0.z, g0.w)));
                float a1 = fmaf(x0[i], g1.x, fmaf(x1[i], g1.y, fmaf(x2[i], g1.z, g1.w)));
                float a2 = fmaf(x0[i], g2.x, fmaf(x1[i], g2.y, fmaf(x2[i], g2.z, g2.w)));
                float a3 = fmaf(x0[i], g3.x, fmaf(x1[i], g3.y, fmaf(x2[i], g3.z, g3.w)));
                const float m01 = fminf(a0, a1);
                const float m23 = fminf(a2, a3);
                accg[i] = fminf(fminf(accg[i], m01), m23);
            }
        }
    }

    const size_t sb = (size_t)B * S;
    #pragma unroll
    for (int i = 0; i < SPT; ++i) {
        const size_t base = (size_t)b * S + s0 + i * BLK;
        partial[(size_t)chunk * sb + base] = hx[i] + accp[i];
        partial[(size_t)(nchunk + chunk) * sb + base] = hx[i] + accg[i];
    }
}

// Kernel 2: per (tile,b): min over chunks, d = sqrt(max(2u,0)), |diff|,
// block-sum -> pb[b*ntile + tile].
__global__ __launch_bounds__(BLK) void sdf_reduce(
    const float* __restrict__ partial, float* __restrict__ pb,
    int B, int S, int nchunk)
{
    const int tile = blockIdx.x;
    const int b    = blockIdx.y;
    const int tid  = threadIdx.x;
    const int s    = tile * BLK + tid;

    const size_t sb = (size_t)B * S;
    const size_t base = (size_t)b * S + s;

    float mp = INF, mg = INF;
    #pragma unroll 8
    for (int c = 0; c < nchunk; ++c) {
        mp = fminf(mp, partial[(size_t)c * sb + base]);
        mg = fminf(mg, partial[(size_t)(nchunk + c) * sb + base]);
    }

    float v = fabsf(sqrtf(fmaxf(2.f * mp, 0.f)) - sqrtf(fmaxf(2.f * mg, 0.f)));

    #pragma unroll
    for (int off = 32; off > 0; off >>= 1)
        v += __shfl_down(v, off, 64);

    __shared__ float wsum[BLK / 64];
    if ((tid & 63) == 0) wsum[tid >> 6] = v;
    __syncthreads();
    if (tid == 0) {
        float t = 0.f;
        #pragma unroll
        for (int w = 0; w < BLK / 64; ++w) t += wsum[w];
        pb[b * gridDim.x + tile] = t;
    }
}

// Kernel 3: final tiny reduction.
__global__ __launch_bounds__(64) void sdf_final(
    const float* __restrict__ pb, float* __restrict__ out,
    int B, int S, int ntile)
{
    const int tid = threadIdx.x;
    float v = (tid < B * ntile) ? pb[tid] : 0.f;
    #pragma unroll
    for (int off = 8; off > 0; off >>= 1)
        v += __shfl_down(v, off, 16);
    if (tid < B * ntile && (tid & 15) == 0)
        out[tid / 16] = v / (float)S;
}

extern "C" void kernel_launch(void* const* d_in, const int* in_sizes, int n_in,
                              void* d_out, int out_size, void* d_ws, size_t ws_size,
                              hipStream_t stream) {
    const float* grid  = (const float*)d_in[0];
    const float* gts   = (const float*)d_in[1];
    const float* preds = (const float*)d_in[2];
    float* out = (float*)d_out;
    float* ws  = (float*)d_ws;

    const int B = 4, S = 4096, N = 4096;

    // partial needs 2*nchunk*B*S floats + 64 floats for pb
    const size_t per_chunk = (size_t)2 * B * S * sizeof(float);  // 128 KB
    int nchunk = 64;
    while (nchunk > 1 &&
           (size_t)nchunk * per_chunk + 256 > ws_size) nchunk >>= 1;
    const int csize = N / nchunk;    // 64 at nchunk=64 (multiple of SUBC)

    float* partial = ws;
    float* pb      = partial + (size_t)2 * nchunk * B * S;

    dim3 g1(S / (BLK * SPT), nchunk, B);   // (4, 64, 4) = 1024 blocks
    sdf_partial_min<<<g1, BLK, 0, stream>>>(grid, gts, preds, partial,
                                            B, S, N, nchunk, csize);
    const int ntile = S / BLK;             // 16
    dim3 g2(ntile, B);
    sdf_reduce<<<g2, BLK, 0, stream>>>(partial, pb, B, S, nchunk);
    sdf_final<<<1, 64, 0, stream>>>(pb, out, B, S, ntile);
}